// Round 18
// baseline (121.220 us; speedup 1.0000x reference)
//
#include <hip/hip_runtime.h>
#include <hip/hip_bf16.h>

#define B_ROWS 16384
#define D_DIM  1024
#define F_DIM  1031
#define KP     1088   // padded K (17 * 64)
#define NP     1152   // padded N / hidden stride (9 * 128)
#define NT_N   9
#define NT_M   128

// k_prep grid layout
#define NB_ROWS_P 512                           // persistent row blocks (2/CU)
#define NTILES    (B_ROWS / 2)                  // 8192 two-row tiles; 16 per block
#define NB_W1T    ((NP * KP + 255) / 256)       // 4896 (direct, 256 elems/block)
#define TILE_BYTES 24576                        // 2 rows x 3 arrays x 4 KB

typedef __attribute__((ext_vector_type(4))) float  f32x4;
typedef __attribute__((ext_vector_type(8))) short  bf16x8;

__device__ __forceinline__ unsigned short f2bf(float f) {
    unsigned int x = __float_as_uint(f);
    unsigned int r = (x + 0x7fffu + ((x >> 16) & 1u)) >> 16;
    return (unsigned short)r;
}
__device__ __forceinline__ float bf2f(unsigned short u) {
    return __uint_as_float((unsigned int)u << 16);
}
__device__ __forceinline__ void gload16(const void* g, void* l) {
    __builtin_amdgcn_global_load_lds(
        (const __attribute__((address_space(1))) void*)g,
        (__attribute__((address_space(3))) void*)l, 16, 0, 0);
}

// Swizzle convention (baked into GLOBAL contents of featpad/w1t):
//   stored[row][c] = logical[row][(c & ~63) + ((c & 63) ^ ((row & 7) << 3))]
// gemm's global_load_lds stays linear; its ds_read XORs byte offset with ((row&7)<<4).

// ---- stage one 2-row tile (h|vc|vb per row, 4 KB chunks) into dst ----
__device__ __forceinline__ void stage_tile(int t, char* dst,
        const float* __restrict__ h, const float* __restrict__ vc,
        const float* __restrict__ vb) {
    int tid = threadIdx.x, wid = tid >> 6;
    #pragma unroll
    for (int r = 0; r < 2; ++r) {
        size_t goff = (size_t)(2 * t + r) * D_DIM + tid * 4;
        gload16(h  + goff, dst + r * 12288 +    0 + wid * 1024);
        gload16(vc + goff, dst + r * 12288 + 4096 + wid * 1024);
        gload16(vb + goff, dst + r * 12288 + 8192 + wid * 1024);
    }
}

// ---- compute one 2-row tile from src. Waves (2w..) pair per row; both waves of a
// row redundantly compute the full-row reduction (no cross-wave combine, no extra
// barrier); each wave converts/stores its half of the bf16 main columns. ----
__device__ __forceinline__ void compute_tile(int t, const char* src,
        unsigned short* __restrict__ featpad) {
    int tid = threadIdx.x, lane = tid & 63, wid = tid >> 6;
    int row_local = wid >> 1, half = wid & 1;
    int row = 2 * t + row_local;
    int s = (row & 7) << 3;
    const char* base = src + row_local * 12288;
    unsigned short* orow = featpad + (size_t)row * KP;

    float nh = 0.f, nc = 0.f, nb = 0.f, dcb = 0.f;
    #pragma unroll
    for (int i = 0; i < 4; ++i) {
        float4 hv = *(const float4*)(base +        i * 1024 + lane * 16);
        float4 cv = *(const float4*)(base + 4096 + i * 1024 + lane * 16);
        float4 bv = *(const float4*)(base + 8192 + i * 1024 + lane * 16);
        nh  += hv.x*hv.x + hv.y*hv.y + hv.z*hv.z + hv.w*hv.w;
        nc  += cv.x*cv.x + cv.y*cv.y + cv.z*cv.z + cv.w*cv.w;
        nb  += bv.x*bv.x + bv.y*bv.y + bv.z*bv.z + bv.w*bv.w;
        dcb += cv.x*bv.x + cv.y*bv.y + cv.z*bv.z + cv.w*bv.w;
        if ((i >> 1) == half) {
            union { unsigned int u[2]; unsigned short us[4]; } w;
            w.us[0] = f2bf(hv.x); w.us[1] = f2bf(hv.y);
            w.us[2] = f2bf(hv.z); w.us[3] = f2bf(hv.w);
            int c0 = i * 256 + lane * 4;
            int st = (c0 & ~63) + ((c0 & 63) ^ s);
            *(uint2*)(orow + st) = *(uint2*)w.u;
        }
    }
    #pragma unroll
    for (int o = 1; o < 64; o <<= 1) {
        nh  += __shfl_xor(nh,  o);
        nc  += __shfl_xor(nc,  o);
        nb  += __shfl_xor(nb,  o);
        dcb += __shfl_xor(dcb, o);
    }

    if (half == 0) {
        float rc = sqrtf(nc), rb = sqrtf(nb), rh = sqrtf(nh);
        float mc = fmaxf(rc, 1e-12f), mb = fmaxf(rb, 1e-12f);
        float align = dcb / (mc * mb);
        float t2 = nc/(mc*mc) - 2.f*dcb/(mc*mb) + nb/(mb*mb);
        t2 = fmaxf(t2, 0.f);
        float scal[7];
        scal[0] = align;
        scal[1] = sqrtf(t2);
        scal[2] = t2;
        scal[3] = sqrtf(fmaxf(nc - 2.f*dcb + nb, 0.f));
        scal[4] = rc; scal[5] = rb; scal[6] = rh;
        int lc = lane ^ s;
        orow[1024 + lane] = f2bf((lc < 7) ? scal[lc] : 0.f);
    }
}

// ---- w1t: DIRECT (r14-proven; staged variant had a boundary bug, no perf gain) ----
__device__ __forceinline__ void prep_w1t(int bid,
        const float* __restrict__ W1, unsigned short* __restrict__ w1t) {
    int idx = bid * 256 + threadIdx.x;
    if (idx >= NP * KP) return;
    int n = idx / KP, c = idx % KP;
    int s = (n & 7) << 3;
    int src_k = (c & ~63) + ((c & 63) ^ s);
    float v = 0.f;
    if (n < F_DIM && src_k < F_DIM) v = W1[(size_t)src_k * F_DIM + n];
    w1t[idx] = f2bf(v);
}

// ---------------- Kernel 1: prep — persistent pipelined rows | direct w1t -------------
__global__ __launch_bounds__(256) void k_prep(
        const float* __restrict__ h, const float* __restrict__ vc,
        const float* __restrict__ vb, const float* __restrict__ W1,
        unsigned short* __restrict__ featpad, unsigned short* __restrict__ w1t) {
    __shared__ __align__(16) char smem[2 * TILE_BYTES];   // 48 KB double buffer
    int bid = blockIdx.x;
    if (bid < NB_ROWS_P) {
        // persistent: 16 tiles, issue-next-before-compute, one barrier per tile
        int buf = 0;
        stage_tile(bid, smem, h, vc, vb);
        __syncthreads();
        for (int t = bid; t < NTILES; t += NB_ROWS_P) {
            int tn = t + NB_ROWS_P;
            if (tn < NTILES) stage_tile(tn, smem + (buf ^ 1) * TILE_BYTES, h, vc, vb);
            compute_tile(t, smem + buf * TILE_BYTES, featpad);
            __syncthreads();   // next tile's loads landed + all reads of buf done
            buf ^= 1;
        }
    } else {
        prep_w1t(bid - NB_ROWS_P, W1, w1t);
    }
}

// ---------------- Kernel 2: GEMM1 (+b1, ReLU) -> bf16 hidden --------------------------
__global__ __launch_bounds__(256, 4) void k_gemm(
        const unsigned short* __restrict__ A,   // featpad [16384][1088] (swizzled)
        const unsigned short* __restrict__ Bt,  // w1t [1152][1088] (swizzled)
        const float* __restrict__ b1,
        unsigned short* __restrict__ hidden) {  // [16384][1152] linear
    __shared__ unsigned short As[128 * 64];   // 16 KB, linear
    __shared__ unsigned short Bs[128 * 64];   // 16 KB, linear
    __shared__ float b1s[128];

    int tid = threadIdx.x;
    int lane = tid & 63;
    int wid = tid >> 6;

    int id = blockIdx.x;            // 0..1151
    int xcd = id & 7;
    int slot = id >> 3;             // 0..143
    int mt = xcd * 16 + slot / NT_N;
    int nt = slot % NT_N;

    if (tid < 128) {
        int ncol = nt * 128 + tid;
        b1s[tid] = (ncol < F_DIM) ? b1[ncol] : 0.f;
    }

    f32x4 acc[4][4] = {};
    int wm = wid >> 1, wn = wid & 1;

    const unsigned short* aSrc = A  + ((size_t)(mt * 128 + wid * 32 + (lane >> 3))) * KP + (lane & 7) * 8;
    const unsigned short* bSrc = Bt + ((size_t)(nt * 128 + wid * 32 + (lane >> 3))) * KP + (lane & 7) * 8;
    unsigned short* aDst = As + wid * 32 * 64;
    unsigned short* bDst = Bs + wid * 32 * 64;

    for (int kt = 0; kt < KP / 64; ++kt) {
        __syncthreads();
        #pragma unroll
        for (int i = 0; i < 4; ++i) {
            gload16(aSrc + kt * 64 + (size_t)i * 8 * KP, aDst + i * 8 * 64);
            gload16(bSrc + kt * 64 + (size_t)i * 8 * KP, bDst + i * 8 * 64);
        }
        __syncthreads();
        #pragma unroll
        for (int kk = 0; kk < 2; ++kk) {
            bf16x8 af[4], bfr[4];
            int klane = kk * 32 + ((lane >> 4) << 3);
            #pragma unroll
            for (int m = 0; m < 4; ++m) {
                int arow = wm * 64 + m * 16 + (lane & 15);
                int abyte = arow * 128 + ((klane * 2) ^ ((arow & 7) << 4));
                af[m] = *(const bf16x8*)((const char*)As + abyte);
            }
            #pragma unroll
            for (int n = 0; n < 4; ++n) {
                int brow = wn * 64 + n * 16 + (lane & 15);
                int bbyte = brow * 128 + ((klane * 2) ^ ((brow & 7) << 4));
                bfr[n] = *(const bf16x8*)((const char*)Bs + bbyte);
            }
            #pragma unroll
            for (int m = 0; m < 4; ++m)
                #pragma unroll
                for (int n = 0; n < 4; ++n)
                    acc[m][n] = __builtin_amdgcn_mfma_f32_16x16x32_bf16(af[m], bfr[n], acc[m][n], 0, 0, 0);
        }
    }

    #pragma unroll
    for (int m = 0; m < 4; ++m) {
        #pragma unroll
        for (int n = 0; n < 4; ++n) {
            int coll = wn * 64 + n * 16 + (lane & 15);
            int col = nt * 128 + coll;
            #pragma unroll
            for (int r = 0; r < 4; ++r) {
                int row = mt * 128 + wm * 64 + m * 16 + ((lane >> 4) << 2) + r;
                float v = acc[m][n][r] + b1s[coll];
                hidden[(size_t)row * NP + col] = f2bf(fmaxf(v, 0.f));
            }
        }
    }
}

// ---------------- Kernel 3: out = hidden @ W2 + b2 (memory-bound stream) -------------
__global__ __launch_bounds__(256) void k_head(const unsigned short* __restrict__ hidden,
                                              const float* __restrict__ W2,
                                              const float* __restrict__ b2,
                                              float* __restrict__ out) {
    __shared__ float W2s[NP * 5];   // 23,040 B
    int tid = threadIdx.x;
    for (int idx = tid; idx < NP * 5; idx += 256) {
        int n = idx / 5, j = idx % 5;
        W2s[idx] = (n < F_DIM) ? W2[n * 5 + j] : 0.f;
    }
    __syncthreads();

    int wid = tid >> 6, lane = tid & 63;
    int row = blockIdx.x * 16 + wid * 4 + (lane >> 4);   // 16 rows/block
    int seg = lane & 15;                                  // 16 lanes per row, 72 cols each
    const unsigned short* hr = hidden + (size_t)row * NP + seg * 72;

    float s[5] = {0.f, 0.f, 0.f, 0.f, 0.f};
    #pragma unroll
    for (int c = 0; c < 9; ++c) {
        union { uint4 v; unsigned short us[8]; } pk;
        pk.v = *(const uint4*)(hr + c * 8);
        #pragma unroll
        for (int e = 0; e < 8; ++e) {
            float hv = bf2f(pk.us[e]);
            int col = seg * 72 + c * 8 + e;
            #pragma unroll
            for (int j = 0; j < 5; ++j) s[j] += hv * W2s[col * 5 + j];
        }
    }
    #pragma unroll
    for (int o = 1; o < 16; o <<= 1) {
        #pragma unroll
        for (int j = 0; j < 5; ++j) s[j] += __shfl_xor(s[j], o);
    }
    if (seg == 0) {
        #pragma unroll
        for (int j = 0; j < 5; ++j) out[(size_t)row * 5 + j] = s[j] + b2[j];
    }
}

extern "C" void kernel_launch(void* const* d_in, const int* in_sizes, int n_in,
                              void* d_out, int out_size, void* d_ws, size_t ws_size,
                              hipStream_t stream) {
    const float* h_final   = (const float*)d_in[0];
    const float* v_current = (const float*)d_in[1];
    const float* v_basin   = (const float*)d_in[2];
    const float* W1        = (const float*)d_in[3];
    const float* b1        = (const float*)d_in[4];
    const float* W2        = (const float*)d_in[5];
    const float* b2        = (const float*)d_in[6];
    float* out = (float*)d_out;

    char* ws = (char*)d_ws;
    unsigned short* featpad = (unsigned short*)ws;                       // 16384*1088*2 = 35,651,584 B
    unsigned short* w1t     = (unsigned short*)(ws + 35651584);          // 1152*1088*2  =  2,506,752 B
    unsigned short* hidden  = (unsigned short*)(ws + 35651584 + 2506752);// 16384*1152*2 = 37,748,736 B

    k_prep<<<dim3(NB_ROWS_P + NB_W1T), dim3(256), 0, stream>>>(
        h_final, v_current, v_basin, W1, featpad, w1t);
    k_gemm<<<dim3(NT_N * NT_M), dim3(256), 0, stream>>>(featpad, w1t, b1, hidden);
    k_head<<<dim3(B_ROWS / 16), dim3(256), 0, stream>>>(hidden, W2, b2, out);
}

// Round 19
// 113.824 us; speedup vs baseline: 1.0650x; 1.0650x over previous
//
#include <hip/hip_runtime.h>
#include <hip/hip_bf16.h>

#define B_ROWS 16384
#define D_DIM  1024
#define F_DIM  1031
#define KP     1088   // padded K (17 * 64)
#define NP     1152   // padded N / hidden stride (9 * 128)
#define NT_N   9
#define NT_M   128

// k_prep grid layout
#define NB_VSTATS (B_ROWS / 4)                  // 4096 (4 rows/block)
#define NB_HCONV  (B_ROWS / 8)                  // 2048 (8 rows/block)
#define NB_W1T    ((NP / 64) * (KP / 64))       // 306 (64x64 staged tiles)

typedef __attribute__((ext_vector_type(4))) float  f32x4;
typedef __attribute__((ext_vector_type(8))) short  bf16x8;

__device__ __forceinline__ unsigned short f2bf(float f) {
    unsigned int x = __float_as_uint(f);
    unsigned int r = (x + 0x7fffu + ((x >> 16) & 1u)) >> 16;
    return (unsigned short)r;
}
__device__ __forceinline__ float bf2f(unsigned short u) {
    return __uint_as_float((unsigned int)u << 16);
}
__device__ __forceinline__ void gload16(const void* g, void* l) {
    __builtin_amdgcn_global_load_lds(
        (const __attribute__((address_space(1))) void*)g,
        (__attribute__((address_space(3))) void*)l, 16, 0, 0);
}

// Swizzle convention (baked into GLOBAL contents of featpad/w1t):
//   stored[row][c] = logical[row][(c & ~63) + ((c & 63) ^ ((row & 7) << 3))]
// gemm's global_load_lds stays linear; its ds_read XORs byte offset with ((row&7)<<4).

// ---- vstats: 4 rows; stage vc+vb (32 KB) via gload16, wave w reduces row w ----------
__device__ __forceinline__ void prep_vstats(int bid, char* smem,
        const float* __restrict__ vc, const float* __restrict__ vb,
        unsigned short* __restrict__ featpad) {
    int tid = threadIdx.x, lane = tid & 63, wid = tid >> 6;
    int row0 = bid * 4;

    #pragma unroll
    for (int r = 0; r < 4; ++r) {
        gload16(vc + (size_t)(row0 + r) * D_DIM + tid * 4, smem + r * 4096 + wid * 1024);
        gload16(vb + (size_t)(row0 + r) * D_DIM + tid * 4, smem + 16384 + r * 4096 + wid * 1024);
    }
    __syncthreads();

    int row = row0 + wid;
    const char* cbase = smem + wid * 4096;
    const char* bbase = smem + 16384 + wid * 4096;
    float nc = 0.f, nb = 0.f, dcb = 0.f;
    #pragma unroll
    for (int i = 0; i < 4; ++i) {
        float4 cv = *(const float4*)(cbase + i * 1024 + lane * 16);
        float4 bv = *(const float4*)(bbase + i * 1024 + lane * 16);
        nc  += cv.x*cv.x + cv.y*cv.y + cv.z*cv.z + cv.w*cv.w;
        nb  += bv.x*bv.x + bv.y*bv.y + bv.z*bv.z + bv.w*bv.w;
        dcb += cv.x*bv.x + cv.y*bv.y + cv.z*bv.z + cv.w*bv.w;
    }
    #pragma unroll
    for (int o = 1; o < 64; o <<= 1) {
        nc  += __shfl_xor(nc,  o);
        nb  += __shfl_xor(nb,  o);
        dcb += __shfl_xor(dcb, o);
    }

    float rc = sqrtf(nc), rb = sqrtf(nb);
    float mc = fmaxf(rc, 1e-12f), mb = fmaxf(rb, 1e-12f);
    float align = dcb / (mc * mb);
    float t2 = nc/(mc*mc) - 2.f*dcb/(mc*mb) + nb/(mb*mb);
    t2 = fmaxf(t2, 0.f);
    float scal[6];
    scal[0] = align;
    scal[1] = sqrtf(t2);
    scal[2] = t2;
    scal[3] = sqrtf(fmaxf(nc - 2.f*dcb + nb, 0.f));
    scal[4] = rc; scal[5] = rb;

    int s = (row & 7) << 3;
    int lc = lane ^ s;
    unsigned short* orow = featpad + (size_t)row * KP;
    if (lc != 6) {
        float v = (lc < 6) ? scal[lc] : 0.f;
        orow[1024 + lane] = f2bf(v);
    }
}

// ---- hconv: 8 rows; stage h (32 KB); wave w: rows 2w,2w+1 (32 lanes each) -----------
__device__ __forceinline__ void prep_hconv(int bid, char* smem,
        const float* __restrict__ h, unsigned short* __restrict__ featpad) {
    int tid = threadIdx.x, lane = tid & 63, wid = tid >> 6;
    int row0 = bid * 8;

    #pragma unroll
    for (int r = 0; r < 8; ++r)
        gload16(h + (size_t)(row0 + r) * D_DIM + tid * 4, smem + r * 4096 + wid * 1024);
    __syncthreads();

    int rowsel = lane >> 5;            // 0/1
    int lane32 = lane & 31;
    int row = row0 + wid * 2 + rowsel;
    int s = (row & 7) << 3;
    const char* hbase = smem + (size_t)(wid * 2 + rowsel) * 4096;
    unsigned short* orow = featpad + (size_t)row * KP;

    float nh = 0.f;
    #pragma unroll
    for (int i = 0; i < 8; ++i) {
        float4 hv = *(const float4*)(hbase + (i * 32 + lane32) * 16);
        nh += hv.x*hv.x + hv.y*hv.y + hv.z*hv.z + hv.w*hv.w;
        union { unsigned int u[2]; unsigned short us[4]; } w;
        w.us[0] = f2bf(hv.x); w.us[1] = f2bf(hv.y);
        w.us[2] = f2bf(hv.z); w.us[3] = f2bf(hv.w);
        int c0 = i * 128 + lane32 * 4;
        int st = (c0 & ~63) | ((c0 & 63) ^ s);
        *(uint2*)(orow + st) = *(uint2*)w.u;
    }
    #pragma unroll
    for (int o = 1; o < 32; o <<= 1) nh += __shfl_xor(nh, o);
    if (lane32 == 0) orow[1024 + (6 ^ s)] = f2bf(sqrtf(nh));
}

// ---- w1t: 64x64 staged tile (r15 structure) + boundary patch.
// r15 bug: staging window for W1's last row crosses the array end (flat
// [1062958,1062962) vs lim=1062961); the clamp zeroed it, corrupting 3 weights at
// (k=1030, n=1028..1030). Fix: detect cells whose staging window crossed the end
// and reload them directly from global (3 cold-path loads total). ----
__device__ __forceinline__ void prep_w1t(int bid, char* smem,
        const float* __restrict__ W1, unsigned short* __restrict__ w1t) {
    int tid = threadIdx.x, wid = tid >> 6;
    int tn = bid / (KP / 64), tk = bid % (KP / 64);
    int n0 = tn * 64, k0 = tk * 64;

    const size_t lim = (size_t)F_DIM * F_DIM;
    #pragma unroll
    for (int j = 0; j < 4; ++j) {
        int krow = k0 + j * 16 + (tid >> 4);
        size_t li = (size_t)krow * F_DIM + n0 + (tid & 15) * 4;
        if (li + 4 > lim) li = 0;   // clamp in-bounds; affected cells patched at write
        gload16(W1 + li, smem + j * 4096 + wid * 1024);
    }
    __syncthreads();

    int n_local = tid >> 2, chunk = tid & 3;
    int n = n0 + n_local;
    int s = (n & 7) << 3;
    const float* lds = (const float*)smem;
    union { uint4 v[2]; unsigned short us[16]; } pk;
    #pragma unroll
    for (int i = 0; i < 16; ++i) {
        int c_local = chunk * 16 + i;
        int src_k = k0 + (c_local ^ s);
        float v = 0.f;
        if (n < F_DIM && src_k < F_DIM) {
            v = lds[(size_t)(c_local ^ s) * 64 + n_local];
            // boundary patch: staging window [src_k*F + (n&~3), +4) crossed lim
            if ((size_t)src_k * F_DIM + (size_t)(n & ~3) + 4 > lim)
                v = W1[(size_t)src_k * F_DIM + n];
        }
        pk.us[i] = f2bf(v);
    }
    unsigned short* orow = w1t + (size_t)n * KP + k0 + chunk * 16;
    *(uint4*)orow = pk.v[0];
    *(uint4*)(orow + 8) = pk.v[1];
}

// ---------------- Kernel 1: fused prep (vstats | hconv | w1t by block range) ----------
__global__ __launch_bounds__(256) void k_prep(
        const float* __restrict__ h, const float* __restrict__ vc,
        const float* __restrict__ vb, const float* __restrict__ W1,
        unsigned short* __restrict__ featpad, unsigned short* __restrict__ w1t) {
    __shared__ __align__(16) char smem[32768];
    int bid = blockIdx.x;
    if (bid < NB_VSTATS) {
        prep_vstats(bid, smem, vc, vb, featpad);
    } else if (bid < NB_VSTATS + NB_HCONV) {
        prep_hconv(bid - NB_VSTATS, smem, h, featpad);
    } else {
        prep_w1t(bid - NB_VSTATS - NB_HCONV, smem, W1, w1t);
    }
}

// ---------------- Kernel 2: GEMM1 (+b1, ReLU) -> bf16 hidden --------------------------
// m97 structure + both-sides swizzle (conflicts=0, r13) + launch_bounds(256,4) (r14).
__global__ __launch_bounds__(256, 4) void k_gemm(
        const unsigned short* __restrict__ A,   // featpad [16384][1088] (swizzled)
        const unsigned short* __restrict__ Bt,  // w1t [1152][1088] (swizzled)
        const float* __restrict__ b1,
        unsigned short* __restrict__ hidden) {  // [16384][1152] linear
    __shared__ unsigned short As[128 * 64];   // 16 KB, linear
    __shared__ unsigned short Bs[128 * 64];   // 16 KB, linear
    __shared__ float b1s[128];

    int tid = threadIdx.x;
    int lane = tid & 63;
    int wid = tid >> 6;

    // XCD-aware mapping (bijective): 9 nt-blocks per A panel on one XCD.
    int id = blockIdx.x;            // 0..1151
    int xcd = id & 7;
    int slot = id >> 3;             // 0..143
    int mt = xcd * 16 + slot / NT_N;
    int nt = slot % NT_N;

    if (tid < 128) {
        int ncol = nt * 128 + tid;
        b1s[tid] = (ncol < F_DIM) ? b1[ncol] : 0.f;
    }

    f32x4 acc[4][4] = {};
    int wm = wid >> 1, wn = wid & 1;

    const unsigned short* aSrc = A  + ((size_t)(mt * 128 + wid * 32 + (lane >> 3))) * KP + (lane & 7) * 8;
    const unsigned short* bSrc = Bt + ((size_t)(nt * 128 + wid * 32 + (lane >> 3))) * KP + (lane & 7) * 8;
    unsigned short* aDst = As + wid * 32 * 64;
    unsigned short* bDst = Bs + wid * 32 * 64;

    for (int kt = 0; kt < KP / 64; ++kt) {
        __syncthreads();
        #pragma unroll
        for (int i = 0; i < 4; ++i) {
            gload16(aSrc + kt * 64 + (size_t)i * 8 * KP, aDst + i * 8 * 64);
            gload16(bSrc + kt * 64 + (size_t)i * 8 * KP, bDst + i * 8 * 64);
        }
        __syncthreads();
        #pragma unroll
        for (int kk = 0; kk < 2; ++kk) {
            bf16x8 af[4], bfr[4];
            int klane = kk * 32 + ((lane >> 4) << 3);
            #pragma unroll
            for (int m = 0; m < 4; ++m) {
                int arow = wm * 64 + m * 16 + (lane & 15);
                int abyte = arow * 128 + ((klane * 2) ^ ((arow & 7) << 4));
                af[m] = *(const bf16x8*)((const char*)As + abyte);
            }
            #pragma unroll
            for (int n = 0; n < 4; ++n) {
                int brow = wn * 64 + n * 16 + (lane & 15);
                int bbyte = brow * 128 + ((klane * 2) ^ ((brow & 7) << 4));
                bfr[n] = *(const bf16x8*)((const char*)Bs + bbyte);
            }
            #pragma unroll
            for (int m = 0; m < 4; ++m)
                #pragma unroll
                for (int n = 0; n < 4; ++n)
                    acc[m][n] = __builtin_amdgcn_mfma_f32_16x16x32_bf16(af[m], bfr[n], acc[m][n], 0, 0, 0);
        }
    }

    #pragma unroll
    for (int m = 0; m < 4; ++m) {
        #pragma unroll
        for (int n = 0; n < 4; ++n) {
            int coll = wn * 64 + n * 16 + (lane & 15);
            int col = nt * 128 + coll;
            #pragma unroll
            for (int r = 0; r < 4; ++r) {
                int row = mt * 128 + wm * 64 + m * 16 + ((lane >> 4) << 2) + r;
                float v = acc[m][n][r] + b1s[coll];
                hidden[(size_t)row * NP + col] = f2bf(fmaxf(v, 0.f));
            }
        }
    }
}

// ---------------- Kernel 3: out = hidden @ W2 + b2 (memory-bound stream) -------------
__global__ __launch_bounds__(256) void k_head(const unsigned short* __restrict__ hidden,
                                              const float* __restrict__ W2,
                                              const float* __restrict__ b2,
                                              float* __restrict__ out) {
    __shared__ float W2s[NP * 5];   // 23,040 B
    int tid = threadIdx.x;
    for (int idx = tid; idx < NP * 5; idx += 256) {
        int n = idx / 5, j = idx % 5;
        W2s[idx] = (n < F_DIM) ? W2[n * 5 + j] : 0.f;
    }
    __syncthreads();

    int wid = tid >> 6, lane = tid & 63;
    int row = blockIdx.x * 16 + wid * 4 + (lane >> 4);   // 16 rows/block
    int seg = lane & 15;                                  // 16 lanes per row, 72 cols each
    const unsigned short* hr = hidden + (size_t)row * NP + seg * 72;

    float s[5] = {0.f, 0.f, 0.f, 0.f, 0.f};
    #pragma unroll
    for (int c = 0; c < 9; ++c) {
        union { uint4 v; unsigned short us[8]; } pk;
        pk.v = *(const uint4*)(hr + c * 8);
        #pragma unroll
        for (int e = 0; e < 8; ++e) {
            float hv = bf2f(pk.us[e]);
            int col = seg * 72 + c * 8 + e;
            #pragma unroll
            for (int j = 0; j < 5; ++j) s[j] += hv * W2s[col * 5 + j];
        }
    }
    #pragma unroll
    for (int o = 1; o < 16; o <<= 1) {
        #pragma unroll
        for (int j = 0; j < 5; ++j) s[j] += __shfl_xor(s[j], o);
    }
    if (seg == 0) {
        #pragma unroll
        for (int j = 0; j < 5; ++j) out[(size_t)row * 5 + j] = s[j] + b2[j];
    }
}

extern "C" void kernel_launch(void* const* d_in, const int* in_sizes, int n_in,
                              void* d_out, int out_size, void* d_ws, size_t ws_size,
                              hipStream_t stream) {
    const float* h_final   = (const float*)d_in[0];
    const float* v_current = (const float*)d_in[1];
    const float* v_basin   = (const float*)d_in[2];
    const float* W1        = (const float*)d_in[3];
    const float* b1        = (const float*)d_in[4];
    const float* W2        = (const float*)d_in[5];
    const float* b2        = (const float*)d_in[6];
    float* out = (float*)d_out;

    char* ws = (char*)d_ws;
    unsigned short* featpad = (unsigned short*)ws;                       // 16384*1088*2 = 35,651,584 B
    unsigned short* w1t     = (unsigned short*)(ws + 35651584);          // 1152*1088*2  =  2,506,752 B
    unsigned short* hidden  = (unsigned short*)(ws + 35651584 + 2506752);// 16384*1152*2 = 37,748,736 B

    k_prep<<<dim3(NB_VSTATS + NB_HCONV + NB_W1T), dim3(256), 0, stream>>>(
        h_final, v_current, v_basin, W1, featpad, w1t);
    k_gemm<<<dim3(NT_N * NT_M), dim3(256), 0, stream>>>(featpad, w1t, b1, hidden);
    k_head<<<dim3(B_ROWS / 16), dim3(256), 0, stream>>>(hidden, W2, b2, out);
}